// Round 2
// 322.695 us; speedup vs baseline: 1.1827x; 1.1827x over previous
//
#include <hip/hip_runtime.h>
#include <math.h>

// ---------------- MS-SSIM on MI355X, round 4 ----------------
// Same structure as round 3 (direct right-halo load -> only 4 up-shuffles/row,
// block-level partial sums, per-level TROWS/WPB templating) but ALL math in
// native ext-vector f2 ops (+ __builtin_elementwise_fma) instead of hand
// v_pk_* inline asm, and round-2-exact SSIM association + predicated-add
// accumulation. Backend may still form v_pk_*_f32 from the v2f32 IR.

typedef float f2 __attribute__((ext_vector_type(2)));

#if __has_builtin(__builtin_elementwise_fma)
static __device__ __forceinline__ f2 vfma(f2 a, f2 b, f2 c) {
    return __builtin_elementwise_fma(a, b, c);
}
#else
static __device__ __forceinline__ f2 vfma(f2 a, f2 b, f2 c) {
    f2 d; d.x = __builtin_fmaf(a.x, b.x, c.x); d.y = __builtin_fmaf(a.y, b.y, c.y);
    return d;
}
#endif

#define C1F 0.0001f
#define C2F 0.0009f
// normalized Gaussian, WIN=5, sigma=1.5
#define GW0f 0.12007838f
#define GW1f 0.23388060f
#define GW2f 0.29208204f

// Horizontal 5-tap conv producing (H(c0), H(c0+1)) from
// VM=(x[c0-2],x[c0-1]), V01=(x[c0],x[c0+1]), V23=(x[c0+2],x[c0+3]):
//   g0 taps: (m2+c2, m1+c3) = VM+V23   (vector)
//   g1 taps: (m1+c1, c0+c2)            (2 scalar adds - cross-element)
//   g2 taps: V01                       (vector)
#define HCONV(DST, VM, V01, V23) do { \
    const f2 t1_ = (VM) + (V23); \
    f2 mid_; mid_.x = (VM).y + (V01).y; mid_.y = (V01).x + (V23).x; \
    (DST) = vfma(G1v, mid_, vfma(G0v, t1_, G2v * (V01))); \
} while (0)

// Vertical 5-tap conv over rolling window slots (static indices).
#define VCONV(OUT, WN, S0,S1,S2,S3,S4) do { \
    const f2 t_ = WN[S0] + WN[S4]; \
    const f2 u_ = WN[S1] + WN[S3]; \
    (OUT) = vfma(G1v, u_, vfma(G0v, t_, G2v * WN[S2])); \
} while (0)

// One row step. J = window slot (= i % 5). S0..S4 = slots of rows i-4..i.
#define ROW(J,S0,S1,S2,S3,S4) do { \
    const int i = i0 + (J); \
    if (i < iters) { \
        const int r = y0 + i - 2; \
        const bool rok = (unsigned)r < (unsigned)H; \
        f2 X01 = {0.f, 0.f}, X23 = {0.f, 0.f}; \
        f2 Z01 = {0.f, 0.f}, Z23 = {0.f, 0.f}; \
        if (rok && g01) { \
            const size_t ro_ = (size_t)r * W + c0; \
            X01 = *(const f2*)(p1 + ro_); \
            Z01 = *(const f2*)(p2 + ro_); \
        } \
        if (rok && g23) { \
            const size_t ro_ = (size_t)r * W + c0 + 2; \
            X23 = *(const f2*)(p1 + ro_); \
            Z23 = *(const f2*)(p2 + ro_); \
        } \
        f2 XM, ZM; \
        XM.x = __shfl_up(X01.x, 1); XM.y = __shfl_up(X01.y, 1); \
        ZM.x = __shfl_up(Z01.x, 1); ZM.y = __shfl_up(Z01.y, 1); \
        const f2 QM  = vfma(ZM,  ZM,  XM * XM); \
        const f2 Q01 = vfma(Z01, Z01, X01 * X01); \
        const f2 Q23 = vfma(Z23, Z23, X23 * X23); \
        const f2 PM  = XM * ZM; \
        const f2 P01 = X01 * Z01; \
        const f2 P23 = X23 * Z23; \
        HCONV(wa[(J)], XM, X01, X23); \
        HCONV(wb[(J)], ZM, Z01, Z23); \
        HCONV(wq[(J)], QM, Q01, Q23); \
        HCONV(wp[(J)], PM, P01, P23); \
        if (i >= 4) { \
            f2 Av, Bv, Qv, Pv; \
            VCONV(Av, wa, S0,S1,S2,S3,S4); \
            VCONV(Bv, wb, S0,S1,S2,S3,S4); \
            VCONV(Qv, wq, S0,S1,S2,S3,S4); \
            VCONV(Pv, wp, S0,S1,S2,S3,S4); \
            const f2 ABv   = Av * Bv; \
            const f2 A2B2v = vfma(Bv, Bv, Av * Av); \
            const f2 S12v  = vfma(TWOv, Pv - ABv, C2v); \
            const f2 SDENv = (Qv - A2B2v) + C2v; \
            const f2 D1v   = A2B2v + C1v; \
            const f2 N1v   = vfma(TWOv, ABv, C1v); \
            const f2 DENv  = D1v * SDENv; \
            f2 RDv; \
            RDv.x = __builtin_amdgcn_rcpf(DENv.x); \
            RDv.y = __builtin_amdgcn_rcpf(DENv.y); \
            const f2 SSv = N1v * S12v * RDv; \
            const f2 CCv = S12v * D1v * RDv; \
            if (vout) { ACCS += SSv; ACCC += CCv; } \
        } \
        if (q1 && (i & 1) && i >= 3 && i <= TROWS + 1 && vout) { \
            const f2 sx_ = X01 + PX; \
            const f2 sz_ = Z01 + PZ; \
            const size_t po_ = (size_t)(r >> 1) * WP + (c0 >> 1); \
            q1[po_] = (sx_.x + sx_.y) * 0.25f; \
            q2[po_] = (sz_.x + sz_.y) * 0.25f; \
        } \
        PX = X01; PZ = Z01; \
    } \
} while (0)

template<int TROWS, int WPB>
__global__ __launch_bounds__(WPB * 64)
void ssim_level_kernel(const float* __restrict__ img1,
                       const float* __restrict__ img2,
                       int H, int W, int SX, int SY,
                       float* __restrict__ pool1,
                       float* __restrict__ pool2,
                       double* __restrict__ block_out)
{
    const int lane = threadIdx.x & 63;
    const int wv   = threadIdx.x >> 6;
    const int w    = blockIdx.x * WPB + wv;

    const int spp   = SX * SY;
    const int plane = w / spp;
    const int rem   = w - plane * spp;
    const int sy    = rem / SX;
    const int sx    = rem - sy * SX;

    const int base = sx * 124;
    const int y0   = sy * TROWS;
    const int c0   = base - 2 + 2 * lane;            // even; lane owns cols c0, c0+1
    // lane 63's loads feed nobody (up-shuffles only) -> mask them off
    const bool g01 = ((unsigned)c0 < (unsigned)W) && (lane < 63);
    const bool g23 = ((unsigned)(c0 + 2) < (unsigned)W) && (lane < 63);
    const bool vout = g01 && (lane >= 1);            // output lanes 1..62

    const float* p1 = img1 + (size_t)plane * H * W;
    const float* p2 = img2 + (size_t)plane * H * W;
    const int WP = W >> 1;
    float* q1 = pool1 ? pool1 + (size_t)plane * (H >> 1) * WP : nullptr;
    float* q2 = pool2 ? pool2 + (size_t)plane * (H >> 1) * WP : nullptr;

    const f2 G0v  = {GW0f, GW0f};
    const f2 G1v  = {GW1f, GW1f};
    const f2 G2v  = {GW2f, GW2f};
    const f2 C1v  = {C1F, C1F};
    const f2 C2v  = {C2F, C2F};
    const f2 TWOv = {2.f, 2.f};

    f2 wa[5], wb[5], wq[5], wp[5];
    f2 PX = {0.f, 0.f}, PZ = {0.f, 0.f};
    f2 ACCS = {0.f, 0.f}, ACCC = {0.f, 0.f};

    const int iters = TROWS + 4;
    for (int i0 = 0; i0 < iters; i0 += 5) {
        ROW(0, 1, 2, 3, 4, 0);
        ROW(1, 2, 3, 4, 0, 1);
        ROW(2, 3, 4, 0, 1, 2);
        ROW(3, 4, 0, 1, 2, 3);
        ROW(4, 0, 1, 2, 3, 4);
    }

    float accs = ACCS.x + ACCS.y;
    float accc = ACCC.x + ACCC.y;
    #pragma unroll
    for (int o = 32; o > 0; o >>= 1) {
        accs += __shfl_down(accs, o, 64);
        accc += __shfl_down(accc, o, 64);
    }

    __shared__ double sred[WPB][2];
    if (lane == 0) { sred[wv][0] = (double)accs; sred[wv][1] = (double)accc; }
    __syncthreads();
    if (threadIdx.x == 0) {
        double s = 0.0, c = 0.0;
        #pragma unroll
        for (int k = 0; k < WPB; ++k) { s += sred[k][0]; c += sred[k][1]; }
        block_out[2 * (size_t)blockIdx.x]     = s;
        block_out[2 * (size_t)blockIdx.x + 1] = c;
    }
}

// per-level block counts / slot offsets (one double2 slot per block)
static constexpr int NBLK[5] = {1920, 576, 384, 384, 384};
static constexpr int BOFF[5] = {0, 1920, 2496, 2880, 3264};   // total 3648

__global__ __launch_bounds__(1024)
void ssim_final_kernel(const double* __restrict__ bsum, float* __restrict__ out)
{
    __shared__ double partial[16][2];
    __shared__ double lvl[5][2];
    const double npx[5] = {96.0*512*512, 96.0*256*256, 96.0*128*128,
                           96.0*64*64,   96.0*32*32};
    const int tid = threadIdx.x, lane = tid & 63, wv = tid >> 6;

    for (int l = 0; l < 5; ++l) {
        double s = 0.0, c = 0.0;
        for (int k = tid; k < NBLK[l]; k += 1024) {
            s += bsum[2 * (size_t)(BOFF[l] + k)];
            c += bsum[2 * (size_t)(BOFF[l] + k) + 1];
        }
        #pragma unroll
        for (int o = 32; o > 0; o >>= 1) {
            s += __shfl_down(s, o, 64);
            c += __shfl_down(c, o, 64);
        }
        if (lane == 0) { partial[wv][0] = s; partial[wv][1] = c; }
        __syncthreads();
        if (tid == 0) {
            double ts = 0.0, tc = 0.0;
            for (int k = 0; k < 16; ++k) { ts += partial[k][0]; tc += partial[k][1]; }
            lvl[l][0] = ts / npx[l];
            lvl[l][1] = tc / npx[l];
        }
        __syncthreads();
    }
    if (tid == 0) {
        const double wgt[5] = {0.0448, 0.2856, 0.3001, 0.2363, 0.1333};
        double ssim4 = (lvl[4][0] + 1.0) * 0.5;
        double P = pow(ssim4, wgt[4]);
        double r = pow((lvl[0][1] + 1.0) * 0.5, wgt[0]) *
                   pow((lvl[1][1] + 1.0) * 0.5, wgt[1]) *
                   pow((lvl[2][1] + 1.0) * 0.5, wgt[2]) *
                   pow((lvl[3][1] + 1.0) * 0.5, wgt[3]);
        r *= P * P * P * P;
        out[0] = (float)r;
    }
}

extern "C" void kernel_launch(void* const* d_in, const int* in_sizes, int n_in,
                              void* d_out, int out_size, void* d_ws, size_t ws_size,
                              hipStream_t stream)
{
    const float* img1 = (const float*)d_in[0];
    const float* img2 = (const float*)d_in[1];
    float* out = (float*)d_out;

    char* ws = (char*)d_ws;
    double* wsum = (double*)ws;                 // 3648 double2 slots (58 KB)
    size_t off = 262144;                        // pooled arrays after 256 KB
    const size_t P = 96;
    float* l1a = (float*)(ws + off); off += P * 256 * 256 * sizeof(float);
    float* l1b = (float*)(ws + off); off += P * 256 * 256 * sizeof(float);
    float* l2a = (float*)(ws + off); off += P * 128 * 128 * sizeof(float);
    float* l2b = (float*)(ws + off); off += P * 128 * 128 * sizeof(float);
    float* l3a = (float*)(ws + off); off += P * 64 * 64 * sizeof(float);
    float* l3b = (float*)(ws + off); off += P * 64 * 64 * sizeof(float);
    float* l4a = (float*)(ws + off); off += P * 32 * 32 * sizeof(float);
    float* l4b = (float*)(ws + off); off += P * 32 * 32 * sizeof(float);

    // L0: 512x512, TROWS=32, SX=5, SY=16 -> 7680 waves, 1920 blocks
    ssim_level_kernel<32, 4><<<1920, 256, 0, stream>>>(
        img1, img2, 512, 512, 5, 16, l1a, l1b, wsum + 2 * (size_t)BOFF[0]);
    // L1: 256x256, TROWS=32, SX=3, SY=8 -> 2304 waves, 576 blocks
    ssim_level_kernel<32, 4><<<576, 256, 0, stream>>>(
        l1a, l1b, 256, 256, 3, 8, l2a, l2b, wsum + 2 * (size_t)BOFF[1]);
    // L2: 128x128, TROWS=16, SX=2, SY=8 -> 1536 waves, 384 blocks
    ssim_level_kernel<16, 4><<<384, 256, 0, stream>>>(
        l2a, l2b, 128, 128, 2, 8, l3a, l3b, wsum + 2 * (size_t)BOFF[2]);
    // L3: 64x64, TROWS=16, SX=1, SY=4 -> 384 waves, 1-wave blocks
    ssim_level_kernel<16, 1><<<384, 64, 0, stream>>>(
        l3a, l3b, 64, 64, 1, 4, l4a, l4b, wsum + 2 * (size_t)BOFF[3]);
    // L4: 32x32, TROWS=8, SX=1, SY=4 -> 384 waves, 1-wave blocks, no pooling
    ssim_level_kernel<8, 1><<<384, 64, 0, stream>>>(
        l4a, l4b, 32, 32, 1, 4, nullptr, nullptr, wsum + 2 * (size_t)BOFF[4]);

    ssim_final_kernel<<<1, 1024, 0, stream>>>(wsum, out);
}

// Round 3
// 300.840 us; speedup vs baseline: 1.2686x; 1.0726x over previous
//
#include <hip/hip_runtime.h>
#include <math.h>

// ---------------- MS-SSIM on MI355X, round 5 ----------------
// Shuffle-free row streaming: each lane loads its own left/right halo
// (float2 at c0-2 / c0 / c0+2; neighbor overlap hits L1), so every lane is
// self-contained -> all 64 lanes produce output (strip width 128, exact
// tiling for W>=128). Wave-uniform row base pointer (SALU) + fixed per-lane
// element offsets kill per-row 64-bit VGPR address math. Zero-padding at
// image edges via precomputed multiply masks (branchless).

typedef float f2 __attribute__((ext_vector_type(2)));

#if __has_builtin(__builtin_elementwise_fma)
static __device__ __forceinline__ f2 vfma(f2 a, f2 b, f2 c) {
    return __builtin_elementwise_fma(a, b, c);
}
#else
static __device__ __forceinline__ f2 vfma(f2 a, f2 b, f2 c) {
    f2 d; d.x = __builtin_fmaf(a.x, b.x, c.x); d.y = __builtin_fmaf(a.y, b.y, c.y);
    return d;
}
#endif

#define C1F 0.0001f
#define C2F 0.0009f
// normalized Gaussian, WIN=5, sigma=1.5
#define GW0f 0.12007838f
#define GW1f 0.23388060f
#define GW2f 0.29208204f

// Horizontal 5-tap conv producing (H(c0), H(c0+1)) from
// VL=(x[c0-2],x[c0-1]), V01=(x[c0],x[c0+1]), VR=(x[c0+2],x[c0+3]):
//   g0 taps: (l0+r0, l1+r1) = VL+VR    (vector)
//   g1 taps: (l1+c1, c0+r0)            (2 scalar adds - cross-element)
//   g2 taps: V01                       (vector)
#define HCONV(DST, VL, V01, VR) do { \
    const f2 t1_ = (VL) + (VR); \
    f2 mid_; mid_.x = (VL).y + (V01).y; mid_.y = (V01).x + (VR).x; \
    (DST) = vfma(G1v, mid_, vfma(G0v, t1_, G2v * (V01))); \
} while (0)

// Vertical 5-tap conv over rolling window slots (static indices).
#define VCONV(OUT, WN, S0,S1,S2,S3,S4) do { \
    const f2 t_ = WN[S0] + WN[S4]; \
    const f2 u_ = WN[S1] + WN[S3]; \
    (OUT) = vfma(G1v, u_, vfma(G0v, t_, G2v * WN[S2])); \
} while (0)

// One row step. J = window slot (= i % 5). S0..S4 = slots of rows i-4..i.
#define ROW(J,S0,S1,S2,S3,S4) do { \
    const int i = i0 + (J); \
    if (i < iters) { \
        const int r = y0 + i - 2; \
        f2 XL = {0.f,0.f}, X01 = {0.f,0.f}, XR = {0.f,0.f}; \
        f2 ZL = {0.f,0.f}, Z01 = {0.f,0.f}, ZR = {0.f,0.f}; \
        if ((unsigned)r < (unsigned)H) { \
            const float* r1_ = p1 + (size_t)r * (size_t)W; \
            const float* r2_ = p2 + (size_t)r * (size_t)W; \
            XL  = *(const f2*)(r1_ + offL) * mL; \
            X01 = *(const f2*)(r1_ + offC); \
            XR  = *(const f2*)(r1_ + offR) * mR; \
            ZL  = *(const f2*)(r2_ + offL) * mL; \
            Z01 = *(const f2*)(r2_ + offC); \
            ZR  = *(const f2*)(r2_ + offR) * mR; \
        } \
        const f2 QL = vfma(ZL,  ZL,  XL  * XL); \
        const f2 QC = vfma(Z01, Z01, X01 * X01); \
        const f2 QR = vfma(ZR,  ZR,  XR  * XR); \
        const f2 PL = XL  * ZL; \
        const f2 PC = X01 * Z01; \
        const f2 PR = XR  * ZR; \
        HCONV(wa[(J)], XL, X01, XR); \
        HCONV(wb[(J)], ZL, Z01, ZR); \
        HCONV(wq[(J)], QL, QC,  QR); \
        HCONV(wp[(J)], PL, PC,  PR); \
        if (i >= 4) { \
            f2 Av, Bv, Qv, Pv; \
            VCONV(Av, wa, S0,S1,S2,S3,S4); \
            VCONV(Bv, wb, S0,S1,S2,S3,S4); \
            VCONV(Qv, wq, S0,S1,S2,S3,S4); \
            VCONV(Pv, wp, S0,S1,S2,S3,S4); \
            const f2 ABv   = Av * Bv; \
            const f2 A2B2v = vfma(Bv, Bv, Av * Av); \
            const f2 S12v  = vfma(TWOv, Pv - ABv, C2v); \
            const f2 SDENv = (Qv - A2B2v) + C2v; \
            const f2 D1v   = A2B2v + C1v; \
            const f2 N1v   = vfma(TWOv, ABv, C1v); \
            const f2 DENv  = D1v * SDENv; \
            f2 RDv; \
            RDv.x = __builtin_amdgcn_rcpf(DENv.x); \
            RDv.y = __builtin_amdgcn_rcpf(DENv.y); \
            const f2 SSv = N1v * S12v * RDv; \
            const f2 CCv = S12v * D1v * RDv; \
            if (gC) { ACCS += SSv; ACCC += CCv; } \
        } \
        if (q1 && (i & 1) && i >= 3 && i <= TROWS + 1 && gC) { \
            const f2 sx_ = X01 + PX; \
            const f2 sz_ = Z01 + PZ; \
            const size_t po_ = (size_t)(r >> 1) * WP + (c0 >> 1); \
            q1[po_] = (sx_.x + sx_.y) * 0.25f; \
            q2[po_] = (sz_.x + sz_.y) * 0.25f; \
        } \
        PX = X01; PZ = Z01; \
    } \
} while (0)

template<int TROWS, int WPB>
__global__ __launch_bounds__(WPB * 64)
void ssim_level_kernel(const float* __restrict__ img1,
                       const float* __restrict__ img2,
                       int H, int W, int SX, int SY,
                       float* __restrict__ pool1,
                       float* __restrict__ pool2,
                       double* __restrict__ block_out)
{
    const int lane = threadIdx.x & 63;
    const int wv   = threadIdx.x >> 6;
    const int w    = blockIdx.x * WPB + wv;

    const int spp   = SX * SY;
    const int plane = w / spp;
    const int rem   = w - plane * spp;
    const int sy    = rem / SX;
    const int sx    = rem - sy * SX;

    const int base = sx * 128;
    const int y0   = sy * TROWS;
    const int c0   = base + 2 * lane;                // lane owns cols c0, c0+1
    const bool gC = (unsigned)c0 < (unsigned)W;      // center cols valid
    const bool gL = (c0 - 2) >= 0 && (c0 - 2) < W;   // left halo in range
    const bool gR = (c0 + 2) < W;                    // right halo in range
    const int offL = gL ? (c0 - 2) : c0;             // clamped safe offsets
    const int offC = gC ? c0 : 0;
    const int offR = gR ? (c0 + 2) : 0;
    const f2 mL = {gL ? 1.f : 0.f, gL ? 1.f : 0.f};
    const f2 mR = {gR ? 1.f : 0.f, gR ? 1.f : 0.f};

    const float* p1 = img1 + (size_t)plane * H * W;
    const float* p2 = img2 + (size_t)plane * H * W;
    const int WP = W >> 1;
    float* q1 = pool1 ? pool1 + (size_t)plane * (H >> 1) * WP : nullptr;
    float* q2 = pool2 ? pool2 + (size_t)plane * (H >> 1) * WP : nullptr;

    const f2 G0v  = {GW0f, GW0f};
    const f2 G1v  = {GW1f, GW1f};
    const f2 G2v  = {GW2f, GW2f};
    const f2 C1v  = {C1F, C1F};
    const f2 C2v  = {C2F, C2F};
    const f2 TWOv = {2.f, 2.f};

    f2 wa[5], wb[5], wq[5], wp[5];
    f2 PX = {0.f, 0.f}, PZ = {0.f, 0.f};
    f2 ACCS = {0.f, 0.f}, ACCC = {0.f, 0.f};

    const int iters = TROWS + 4;
    for (int i0 = 0; i0 < iters; i0 += 5) {
        ROW(0, 1, 2, 3, 4, 0);
        ROW(1, 2, 3, 4, 0, 1);
        ROW(2, 3, 4, 0, 1, 2);
        ROW(3, 4, 0, 1, 2, 3);
        ROW(4, 0, 1, 2, 3, 4);
    }

    float accs = ACCS.x + ACCS.y;
    float accc = ACCC.x + ACCC.y;
    #pragma unroll
    for (int o = 32; o > 0; o >>= 1) {
        accs += __shfl_down(accs, o, 64);
        accc += __shfl_down(accc, o, 64);
    }

    __shared__ double sred[WPB][2];
    if (lane == 0) { sred[wv][0] = (double)accs; sred[wv][1] = (double)accc; }
    __syncthreads();
    if (threadIdx.x == 0) {
        double s = 0.0, c = 0.0;
        #pragma unroll
        for (int k = 0; k < WPB; ++k) { s += sred[k][0]; c += sred[k][1]; }
        block_out[2 * (size_t)blockIdx.x]     = s;
        block_out[2 * (size_t)blockIdx.x + 1] = c;
    }
}

// per-level block counts / slot offsets (one double2 slot per block)
static constexpr int NBLK[5] = {1536, 768, 384, 384, 192};
static constexpr int BOFF[5] = {0, 1536, 2304, 2688, 3072};   // total 3264

__global__ __launch_bounds__(1024)
void ssim_final_kernel(const double* __restrict__ bsum, float* __restrict__ out)
{
    __shared__ double partial[16][2];
    __shared__ double lvl[5][2];
    const double npx[5] = {96.0*512*512, 96.0*256*256, 96.0*128*128,
                           96.0*64*64,   96.0*32*32};
    const int tid = threadIdx.x, lane = tid & 63, wv = tid >> 6;

    for (int l = 0; l < 5; ++l) {
        double s = 0.0, c = 0.0;
        for (int k = tid; k < NBLK[l]; k += 1024) {
            s += bsum[2 * (size_t)(BOFF[l] + k)];
            c += bsum[2 * (size_t)(BOFF[l] + k) + 1];
        }
        #pragma unroll
        for (int o = 32; o > 0; o >>= 1) {
            s += __shfl_down(s, o, 64);
            c += __shfl_down(c, o, 64);
        }
        if (lane == 0) { partial[wv][0] = s; partial[wv][1] = c; }
        __syncthreads();
        if (tid == 0) {
            double ts = 0.0, tc = 0.0;
            for (int k = 0; k < 16; ++k) { ts += partial[k][0]; tc += partial[k][1]; }
            lvl[l][0] = ts / npx[l];
            lvl[l][1] = tc / npx[l];
        }
        __syncthreads();
    }
    if (tid == 0) {
        const double wgt[5] = {0.0448, 0.2856, 0.3001, 0.2363, 0.1333};
        double ssim4 = (lvl[4][0] + 1.0) * 0.5;
        double P = pow(ssim4, wgt[4]);
        double r = pow((lvl[0][1] + 1.0) * 0.5, wgt[0]) *
                   pow((lvl[1][1] + 1.0) * 0.5, wgt[1]) *
                   pow((lvl[2][1] + 1.0) * 0.5, wgt[2]) *
                   pow((lvl[3][1] + 1.0) * 0.5, wgt[3]);
        r *= P * P * P * P;
        out[0] = (float)r;
    }
}

extern "C" void kernel_launch(void* const* d_in, const int* in_sizes, int n_in,
                              void* d_out, int out_size, void* d_ws, size_t ws_size,
                              hipStream_t stream)
{
    const float* img1 = (const float*)d_in[0];
    const float* img2 = (const float*)d_in[1];
    float* out = (float*)d_out;

    char* ws = (char*)d_ws;
    double* wsum = (double*)ws;                 // 3264 double2 slots (52 KB)
    size_t off = 262144;                        // pooled arrays after 256 KB
    const size_t P = 96;
    float* l1a = (float*)(ws + off); off += P * 256 * 256 * sizeof(float);
    float* l1b = (float*)(ws + off); off += P * 256 * 256 * sizeof(float);
    float* l2a = (float*)(ws + off); off += P * 128 * 128 * sizeof(float);
    float* l2b = (float*)(ws + off); off += P * 128 * 128 * sizeof(float);
    float* l3a = (float*)(ws + off); off += P * 64 * 64 * sizeof(float);
    float* l3b = (float*)(ws + off); off += P * 64 * 64 * sizeof(float);
    float* l4a = (float*)(ws + off); off += P * 32 * 32 * sizeof(float);
    float* l4b = (float*)(ws + off); off += P * 32 * 32 * sizeof(float);

    // L0: 512x512, TROWS=32, SX=4, SY=16 -> 6144 waves, 1536 blocks
    ssim_level_kernel<32, 4><<<1536, 256, 0, stream>>>(
        img1, img2, 512, 512, 4, 16, l1a, l1b, wsum + 2 * (size_t)BOFF[0]);
    // L1: 256x256, TROWS=16, SX=2, SY=16 -> 3072 waves, 768 blocks
    ssim_level_kernel<16, 4><<<768, 256, 0, stream>>>(
        l1a, l1b, 256, 256, 2, 16, l2a, l2b, wsum + 2 * (size_t)BOFF[1]);
    // L2: 128x128, TROWS=8, SX=1, SY=16 -> 1536 waves, 384 blocks
    ssim_level_kernel<8, 4><<<384, 256, 0, stream>>>(
        l2a, l2b, 128, 128, 1, 16, l3a, l3b, wsum + 2 * (size_t)BOFF[2]);
    // L3: 64x64, TROWS=4, SX=1, SY=16 -> 1536 waves, 384 blocks
    ssim_level_kernel<4, 4><<<384, 256, 0, stream>>>(
        l3a, l3b, 64, 64, 1, 16, l4a, l4b, wsum + 2 * (size_t)BOFF[3]);
    // L4: 32x32, TROWS=4, SX=1, SY=8 -> 768 waves, 192 blocks, no pooling
    ssim_level_kernel<4, 4><<<192, 256, 0, stream>>>(
        l4a, l4b, 32, 32, 1, 8, nullptr, nullptr, wsum + 2 * (size_t)BOFF[4]);

    ssim_final_kernel<<<1, 1024, 0, stream>>>(wsum, out);
}

// Round 4
// 291.063 us; speedup vs baseline: 1.3112x; 1.0336x over previous
//
#include <hip/hip_runtime.h>
#include <math.h>

// ---------------- MS-SSIM on MI355X, round 6 ----------------
// Round-5 structure (shuffle-free, direct halo loads, all-64-lane strips)
// plus: BRANCHLESS row handling (clamped row index + row-valid multiply mask
// folded into the column masks) so every load is speculation-safe, and a
// fully-unrolled row loop so the compiler can cluster/pipeline loads across
// rows. L0 runs TROWS=16 for 2x wave count (latency hiding).

typedef float f2 __attribute__((ext_vector_type(2)));

#if __has_builtin(__builtin_elementwise_fma)
static __device__ __forceinline__ f2 vfma(f2 a, f2 b, f2 c) {
    return __builtin_elementwise_fma(a, b, c);
}
#else
static __device__ __forceinline__ f2 vfma(f2 a, f2 b, f2 c) {
    f2 d; d.x = __builtin_fmaf(a.x, b.x, c.x); d.y = __builtin_fmaf(a.y, b.y, c.y);
    return d;
}
#endif

#define C1F 0.0001f
#define C2F 0.0009f
// normalized Gaussian, WIN=5, sigma=1.5
#define GW0f 0.12007838f
#define GW1f 0.23388060f
#define GW2f 0.29208204f

// Horizontal 5-tap conv producing (H(c0), H(c0+1)) from
// VL=(x[c0-2],x[c0-1]), V01=(x[c0],x[c0+1]), VR=(x[c0+2],x[c0+3])
#define HCONV(DST, VL, V01, VR) do { \
    const f2 t1_ = (VL) + (VR); \
    f2 mid_; mid_.x = (VL).y + (V01).y; mid_.y = (V01).x + (VR).x; \
    (DST) = vfma(G1v, mid_, vfma(G0v, t1_, G2v * (V01))); \
} while (0)

// Vertical 5-tap conv over rolling window slots (static indices).
#define VCONV(OUT, WN, S0,S1,S2,S3,S4) do { \
    const f2 t_ = WN[S0] + WN[S4]; \
    const f2 u_ = WN[S1] + WN[S3]; \
    (OUT) = vfma(G1v, u_, vfma(G0v, t_, G2v * WN[S2])); \
} while (0)

// One row step. J = window slot (= i % 5). S0..S4 = slots of rows i-4..i.
// Branch-free: row index clamped (always-safe loads), vertical zero-padding
// via multiply mask mVv folded into column masks.
#define ROW(J,S0,S1,S2,S3,S4) do { \
    const int i = i0 + (J); \
    if (i < iters) { \
        const int r = y0 + i - 2; \
        const int rc = min(max(r, 0), H - 1); \
        const float rvf = ((unsigned)r < (unsigned)H) ? 1.f : 0.f; \
        const f2 mVv = {rvf, rvf}; \
        const f2 mLV = mL * mVv; \
        const f2 mRV = mR * mVv; \
        const float* r1_ = p1 + (size_t)rc * (size_t)W; \
        const float* r2_ = p2 + (size_t)rc * (size_t)W; \
        const f2 XL  = *(const f2*)(r1_ + offL) * mLV; \
        const f2 X01 = *(const f2*)(r1_ + offC) * mVv; \
        const f2 XR  = *(const f2*)(r1_ + offR) * mRV; \
        const f2 ZL  = *(const f2*)(r2_ + offL) * mLV; \
        const f2 Z01 = *(const f2*)(r2_ + offC) * mVv; \
        const f2 ZR  = *(const f2*)(r2_ + offR) * mRV; \
        const f2 QL = vfma(ZL,  ZL,  XL  * XL); \
        const f2 QC = vfma(Z01, Z01, X01 * X01); \
        const f2 QR = vfma(ZR,  ZR,  XR  * XR); \
        const f2 PL = XL  * ZL; \
        const f2 PC = X01 * Z01; \
        const f2 PR = XR  * ZR; \
        HCONV(wa[(J)], XL, X01, XR); \
        HCONV(wb[(J)], ZL, Z01, ZR); \
        HCONV(wq[(J)], QL, QC,  QR); \
        HCONV(wp[(J)], PL, PC,  PR); \
        if (i >= 4) { \
            f2 Av, Bv, Qv, Pv; \
            VCONV(Av, wa, S0,S1,S2,S3,S4); \
            VCONV(Bv, wb, S0,S1,S2,S3,S4); \
            VCONV(Qv, wq, S0,S1,S2,S3,S4); \
            VCONV(Pv, wp, S0,S1,S2,S3,S4); \
            const f2 ABv   = Av * Bv; \
            const f2 A2B2v = vfma(Bv, Bv, Av * Av); \
            const f2 S12v  = vfma(TWOv, Pv - ABv, C2v); \
            const f2 SDENv = (Qv - A2B2v) + C2v; \
            const f2 D1v   = A2B2v + C1v; \
            const f2 N1v   = vfma(TWOv, ABv, C1v); \
            const f2 DENv  = D1v * SDENv; \
            f2 RDv; \
            RDv.x = __builtin_amdgcn_rcpf(DENv.x); \
            RDv.y = __builtin_amdgcn_rcpf(DENv.y); \
            const f2 SSv = N1v * S12v * RDv; \
            const f2 CCv = S12v * D1v * RDv; \
            if (gC) { ACCS += SSv; ACCC += CCv; } \
        } \
        if (q1 && (i & 1) && i >= 3 && i <= TROWS + 1 && gC) { \
            const f2 sx_ = X01 + PX; \
            const f2 sz_ = Z01 + PZ; \
            const size_t po_ = (size_t)(r >> 1) * WP + (c0 >> 1); \
            q1[po_] = (sx_.x + sx_.y) * 0.25f; \
            q2[po_] = (sz_.x + sz_.y) * 0.25f; \
        } \
        PX = X01; PZ = Z01; \
    } \
} while (0)

template<int TROWS, int WPB>
__global__ __launch_bounds__(WPB * 64)
void ssim_level_kernel(const float* __restrict__ img1,
                       const float* __restrict__ img2,
                       int H, int W, int SX, int SY,
                       float* __restrict__ pool1,
                       float* __restrict__ pool2,
                       double* __restrict__ block_out)
{
    const int lane = threadIdx.x & 63;
    const int wv   = threadIdx.x >> 6;
    const int w    = blockIdx.x * WPB + wv;

    const int spp   = SX * SY;
    const int plane = w / spp;
    const int rem   = w - plane * spp;
    const int sy    = rem / SX;
    const int sx    = rem - sy * SX;

    const int base = sx * 128;
    const int y0   = sy * TROWS;
    const int c0   = base + 2 * lane;                // lane owns cols c0, c0+1
    const bool gC = (unsigned)c0 < (unsigned)W;      // center cols valid
    const bool gL = (c0 - 2) >= 0 && (c0 - 2) < W;   // left halo in range
    const bool gR = (c0 + 2) < W;                    // right halo in range
    const int offL = gL ? (c0 - 2) : 0;              // clamped safe offsets
    const int offC = gC ? c0 : 0;
    const int offR = gR ? (c0 + 2) : 0;
    const f2 mL = {gL ? 1.f : 0.f, gL ? 1.f : 0.f};
    const f2 mR = {gR ? 1.f : 0.f, gR ? 1.f : 0.f};

    const float* p1 = img1 + (size_t)plane * H * W;
    const float* p2 = img2 + (size_t)plane * H * W;
    const int WP = W >> 1;
    float* q1 = pool1 ? pool1 + (size_t)plane * (H >> 1) * WP : nullptr;
    float* q2 = pool2 ? pool2 + (size_t)plane * (H >> 1) * WP : nullptr;

    const f2 G0v  = {GW0f, GW0f};
    const f2 G1v  = {GW1f, GW1f};
    const f2 G2v  = {GW2f, GW2f};
    const f2 C1v  = {C1F, C1F};
    const f2 C2v  = {C2F, C2F};
    const f2 TWOv = {2.f, 2.f};

    f2 wa[5], wb[5], wq[5], wp[5];
    f2 PX = {0.f, 0.f}, PZ = {0.f, 0.f};
    f2 ACCS = {0.f, 0.f}, ACCC = {0.f, 0.f};

    const int iters = TROWS + 4;
    #pragma unroll
    for (int i0 = 0; i0 < iters; i0 += 5) {
        ROW(0, 1, 2, 3, 4, 0);
        ROW(1, 2, 3, 4, 0, 1);
        ROW(2, 3, 4, 0, 1, 2);
        ROW(3, 4, 0, 1, 2, 3);
        ROW(4, 0, 1, 2, 3, 4);
    }

    float accs = ACCS.x + ACCS.y;
    float accc = ACCC.x + ACCC.y;
    #pragma unroll
    for (int o = 32; o > 0; o >>= 1) {
        accs += __shfl_down(accs, o, 64);
        accc += __shfl_down(accc, o, 64);
    }

    __shared__ double sred[WPB][2];
    if (lane == 0) { sred[wv][0] = (double)accs; sred[wv][1] = (double)accc; }
    __syncthreads();
    if (threadIdx.x == 0) {
        double s = 0.0, c = 0.0;
        #pragma unroll
        for (int k = 0; k < WPB; ++k) { s += sred[k][0]; c += sred[k][1]; }
        block_out[2 * (size_t)blockIdx.x]     = s;
        block_out[2 * (size_t)blockIdx.x + 1] = c;
    }
}

// per-level block counts / slot offsets (one double2 slot per block)
static constexpr int NBLK[5] = {3072, 768, 384, 384, 192};
static constexpr int BOFF[5] = {0, 3072, 3840, 4224, 4608};   // total 4800

__global__ __launch_bounds__(1024)
void ssim_final_kernel(const double* __restrict__ bsum, float* __restrict__ out)
{
    __shared__ double partial[16][2];
    __shared__ double lvl[5][2];
    const double npx[5] = {96.0*512*512, 96.0*256*256, 96.0*128*128,
                           96.0*64*64,   96.0*32*32};
    const int tid = threadIdx.x, lane = tid & 63, wv = tid >> 6;

    for (int l = 0; l < 5; ++l) {
        double s = 0.0, c = 0.0;
        for (int k = tid; k < NBLK[l]; k += 1024) {
            s += bsum[2 * (size_t)(BOFF[l] + k)];
            c += bsum[2 * (size_t)(BOFF[l] + k) + 1];
        }
        #pragma unroll
        for (int o = 32; o > 0; o >>= 1) {
            s += __shfl_down(s, o, 64);
            c += __shfl_down(c, o, 64);
        }
        if (lane == 0) { partial[wv][0] = s; partial[wv][1] = c; }
        __syncthreads();
        if (tid == 0) {
            double ts = 0.0, tc = 0.0;
            for (int k = 0; k < 16; ++k) { ts += partial[k][0]; tc += partial[k][1]; }
            lvl[l][0] = ts / npx[l];
            lvl[l][1] = tc / npx[l];
        }
        __syncthreads();
    }
    if (tid == 0) {
        const double wgt[5] = {0.0448, 0.2856, 0.3001, 0.2363, 0.1333};
        double ssim4 = (lvl[4][0] + 1.0) * 0.5;
        double P = pow(ssim4, wgt[4]);
        double r = pow((lvl[0][1] + 1.0) * 0.5, wgt[0]) *
                   pow((lvl[1][1] + 1.0) * 0.5, wgt[1]) *
                   pow((lvl[2][1] + 1.0) * 0.5, wgt[2]) *
                   pow((lvl[3][1] + 1.0) * 0.5, wgt[3]);
        r *= P * P * P * P;
        out[0] = (float)r;
    }
}

extern "C" void kernel_launch(void* const* d_in, const int* in_sizes, int n_in,
                              void* d_out, int out_size, void* d_ws, size_t ws_size,
                              hipStream_t stream)
{
    const float* img1 = (const float*)d_in[0];
    const float* img2 = (const float*)d_in[1];
    float* out = (float*)d_out;

    char* ws = (char*)d_ws;
    double* wsum = (double*)ws;                 // 4800 double2 slots (77 KB)
    size_t off = 262144;                        // pooled arrays after 256 KB
    const size_t P = 96;
    float* l1a = (float*)(ws + off); off += P * 256 * 256 * sizeof(float);
    float* l1b = (float*)(ws + off); off += P * 256 * 256 * sizeof(float);
    float* l2a = (float*)(ws + off); off += P * 128 * 128 * sizeof(float);
    float* l2b = (float*)(ws + off); off += P * 128 * 128 * sizeof(float);
    float* l3a = (float*)(ws + off); off += P * 64 * 64 * sizeof(float);
    float* l3b = (float*)(ws + off); off += P * 64 * 64 * sizeof(float);
    float* l4a = (float*)(ws + off); off += P * 32 * 32 * sizeof(float);
    float* l4b = (float*)(ws + off); off += P * 32 * 32 * sizeof(float);

    // L0: 512x512, TROWS=16, SX=4, SY=32 -> 12288 waves, 3072 blocks
    ssim_level_kernel<16, 4><<<3072, 256, 0, stream>>>(
        img1, img2, 512, 512, 4, 32, l1a, l1b, wsum + 2 * (size_t)BOFF[0]);
    // L1: 256x256, TROWS=16, SX=2, SY=16 -> 3072 waves, 768 blocks
    ssim_level_kernel<16, 4><<<768, 256, 0, stream>>>(
        l1a, l1b, 256, 256, 2, 16, l2a, l2b, wsum + 2 * (size_t)BOFF[1]);
    // L2: 128x128, TROWS=8, SX=1, SY=16 -> 1536 waves, 384 blocks
    ssim_level_kernel<8, 4><<<384, 256, 0, stream>>>(
        l2a, l2b, 128, 128, 1, 16, l3a, l3b, wsum + 2 * (size_t)BOFF[2]);
    // L3: 64x64, TROWS=4, SX=1, SY=16 -> 1536 waves, 384 blocks
    ssim_level_kernel<4, 4><<<384, 256, 0, stream>>>(
        l3a, l3b, 64, 64, 1, 16, l4a, l4b, wsum + 2 * (size_t)BOFF[3]);
    // L4: 32x32, TROWS=4, SX=1, SY=8 -> 768 waves, 192 blocks, no pooling
    ssim_level_kernel<4, 4><<<192, 256, 0, stream>>>(
        l4a, l4b, 32, 32, 1, 8, nullptr, nullptr, wsum + 2 * (size_t)BOFF[4]);

    ssim_final_kernel<<<1, 1024, 0, stream>>>(wsum, out);
}